// Round 1
// 396.633 us; speedup vs baseline: 1.0074x; 1.0074x over previous
//
#include <hip/hip_runtime.h>

// ============================================================================
// MixerBlock (attention QK^T/softmax is dead code; heads = V only):
//   x1 = LN1(patches); sa = x1 @ Wc^T + bc  (Wc = out_w @ Wv, precomputed)
//   x2 = sa + x1 (bf16, ws); x3 = LN2(x2)
//   h = selu(x3 @ w1^T + b1); out = h @ w2^T + b2 + x3
// R7 changes vs R6:
//   - gemm: ported to the 256x256 / BK=64 8-phase schedule (T2+T3+T4+T5):
//     8 waves 2x4, wave tile 128x64, acc[8][4], 128 KiB LDS (2 K-tile bufs).
//     Per phase: 8 ds_read_b128 + stage 1 region (2 global_load_lds) +
//     counted vmcnt(4) at phases 4/8 only + barrier + lgkmcnt(0) +
//     setprio(1) around 16 MFMA + barrier.  (R6: one barrier per BK=32 step,
//     MfmaUtil capped at 30% -- schedule-bound, all counters low.)
//   - K-tile regions: A-m0/A-m1 (row-halves per wave) and B-k0/B-k1
//     (k-panels), 16 KB = 2 loads/thread each. Stage slots chosen so every
//     overwrite lands >=1 barrier after the region's last read (verified
//     phase-by-phase); vmcnt(4) @P4/P8 guarantees each tile landed before
//     its first read. Tail iter: stages only P1/P2, vmcnt(0) drain @P4.
// Kept: 16x16x32 MFMA, chunk swizzle (0 bank conflicts), global_load_lds
// width 16, XCD m-band remap, bf16 X2 residency, merged casts.
// ============================================================================

typedef __bf16 bf16;
typedef __bf16 bf16x8 __attribute__((ext_vector_type(8)));
typedef __bf16 bf16x4 __attribute__((ext_vector_type(4)));
typedef float  f32x4  __attribute__((ext_vector_type(4)));

#define N_ROWS  16384   // B*S = 8*2048

#define AS1(p) ((const __attribute__((address_space(1))) void*)(p))
#define AS3(p) ((__attribute__((address_space(3))) void*)(p))

// s_waitcnt imm (gfx9): vmcnt[3:0]|[15:14], expcnt[6:4]=7, lgkmcnt[11:8]=0xF
#define VM4 0x0F74
#define VM0 0x0F70

// ---------------------------------------------------------------------------
// merged fp32->bf16 casts: mlp_w1 | mlp_w2 | out_w (4 elems/thread)
#define N1 589824   // 3072*768/4
#define N2 589824   // 768*3072/4
#define N3 147456   // 768*768/4
__global__ __launch_bounds__(256) void prep_cast(const float* __restrict__ w1,
                                                 const float* __restrict__ w2,
                                                 const float* __restrict__ ow,
                                                 bf16* __restrict__ w1b,
                                                 bf16* __restrict__ w2b,
                                                 bf16* __restrict__ owb) {
  int i = blockIdx.x * 256 + threadIdx.x;
  const float* src; bf16* dst; int off;
  if (i < N1)           { src = w1; dst = w1b; off = i; }
  else if (i < N1 + N2) { src = w2; dst = w2b; off = i - N1; }
  else                  { src = ow; dst = owb; off = i - N1 - N2; }
  float4 v = ((const float4*)src)[off];
  bf16x4 o = {(bf16)v.x, (bf16)v.y, (bf16)v.z, (bf16)v.w};
  *(bf16x4*)(dst + 4 * (size_t)off) = o;
}

// ---------------------------------------------------------------------------
// WvT[k][j] = in_weight[(j*3+2)*768 + k], LDS-tiled 64x64 (coalesced both ways)
__global__ __launch_bounds__(256) void wvt_kernel(const float* __restrict__ in_weight,
                                                  bf16* __restrict__ wvt) {
  __shared__ float t[64][65];
  const int k0 = blockIdx.x * 64, j0 = blockIdx.y * 64;
  const int tx = threadIdx.x & 63, ty = threadIdx.x >> 6;
  for (int jj = ty; jj < 64; jj += 4)
    t[jj][tx] = in_weight[((size_t)(j0 + jj) * 3 + 2) * 768 + k0 + tx];
  __syncthreads();
  for (int kk = ty; kk < 64; kk += 4)
    wvt[(size_t)(k0 + kk) * 768 + j0 + tx] = (bf16)t[tx][kk];
}

// ---------------------------------------------------------------------------
__global__ __launch_bounds__(64) void bias_combine_kernel(const float* __restrict__ out_w,
                                                          const float* __restrict__ in_bias,
                                                          const float* __restrict__ out_b,
                                                          float* __restrict__ bc) {
  int n = blockIdx.x, l = threadIdx.x;
  float s = 0.f;
  for (int j = l; j < 768; j += 64) s += out_w[(size_t)n * 768 + j] * in_bias[j * 3 + 2];
#pragma unroll
  for (int off = 32; off > 0; off >>= 1) s += __shfl_xor(s, off, 64);
  if (l == 0) bc[n] = s + out_b[n];
}

// ---------------------------------------------------------------------------
// LayerNorm: one row (768) per 256-thread block. TIN = float or bf16.
template <typename TIN>
__global__ __launch_bounds__(256) void ln_kernel(const TIN* __restrict__ x,
                                                 const float* __restrict__ g,
                                                 const float* __restrict__ b,
                                                 bf16* __restrict__ y) {
  const int row = blockIdx.x;
  const TIN* xr = x + (size_t)row * 768;
  float v[3], s1 = 0.f, s2 = 0.f;
#pragma unroll
  for (int i = 0; i < 3; ++i) {
    v[i] = (float)xr[threadIdx.x + i * 256];
    s1 += v[i];
    s2 += v[i] * v[i];
  }
#pragma unroll
  for (int off = 32; off > 0; off >>= 1) {
    s1 += __shfl_xor(s1, off, 64);
    s2 += __shfl_xor(s2, off, 64);
  }
  __shared__ float red[8];
  int w = threadIdx.x >> 6, l = threadIdx.x & 63;
  if (l == 0) { red[w * 2] = s1; red[w * 2 + 1] = s2; }
  __syncthreads();
  s1 = red[0] + red[2] + red[4] + red[6];
  s2 = red[1] + red[3] + red[5] + red[7];
  const float mu = s1 * (1.f / 768.f);
  const float var = s2 * (1.f / 768.f) - mu * mu;
  const float rstd = rsqrtf(var + 1e-5f);
#pragma unroll
  for (int i = 0; i < 3; ++i) {
    int d = threadIdx.x + i * 256;
    y[(size_t)row * 768 + d] = (bf16)((v[i] - mu) * rstd * g[d] + b[d]);
  }
}

// ---------------------------------------------------------------------------
// C[M][N] = A[M][K] @ B[N][K]^T (+ epilogue). Block tile 256x256, BK=64,
// 512 threads = 8 waves (2x4), wave tile 128x64, acc[8][4].
// 8-phase schedule over 2 K-tiles (double-buffered 128 KiB LDS).
// LDS per buffer: A [2 k-panels][256 rows][32 k] + B same, chunk-swizzled
// (stored 16B chunk sc at row r holds logical chunk (sc-(r>>1))&3).
// Regions (16 KB, 2 loads/thread): A-m0 = each wave's rows 0-63
// (block rows 0-63 u 128-191), A-m1 = rows 64-127 u 192-255, B-k0/B-k1 =
// k-panels. Phase (mh,ks) reads A-m(mh) panel ks + B-k(ks).
// Requires K % 128 == 0, K >= 256; M,N % 256 == 0.
// EPI 0: bf16=acc | EPI 1: f32=acc+bias+resid | EPI 2: bf16=selu(acc+bias)
// EPI 3: bf16=acc+bias+resid
template <int EPI>
__global__ __launch_bounds__(512, 2) void gemm_bt(const bf16* __restrict__ A,
                                                  const bf16* __restrict__ B,
                                                  const float* __restrict__ bias,
                                                  const bf16* __restrict__ resid,
                                                  void* __restrict__ out,
                                                  int M, int N, int K) {
  __shared__ bf16 ring[65536];   // 128 KiB = 2 bufs x (A 16384 + B 16384 elems)
  const int tid = threadIdx.x;
  const int w = tid >> 6, l = tid & 63;
  const int wr = w >> 2, wcn = w & 3;       // 2x4 wave grid
  const int q = l >> 4, m16 = l & 15;

  // XCD-aware remap (XCD = linear%8): each XCD owns a contiguous band of
  // gridy/8 m-strips, m fastest -> A band L2-resident across n-tiles.
  int mtile, ntile;
  {
    const int L = blockIdx.y * gridDim.x + blockIdx.x;
    const int gy = gridDim.y;
    if ((gy & 7) == 0) {
      const int mpx = gy >> 3;
      const int xcd = L & 7;
      const int slot = L >> 3;
      mtile = xcd * mpx + (slot % mpx);
      ntile = slot / mpx;
    } else {
      mtile = blockIdx.y; ntile = blockIdx.x;
    }
  }
  const long tileM = (long)mtile * 256;
  const long tileN = (long)ntile * 256;

  // staging geometry: per region 16 blocks of 1 KB (16 rows x 64 B), block
  // b = w*2+j; lane l covers row (l>>2), stored chunk (l&3) -> LDS dest is
  // wave-uniform base + l*16B (global_load_lds constraint). Global source is
  // pre-swizzled per-lane.
  const bf16* gA[2][2]; const bf16* gB[2][2];   // [mh|ks][j]
  int lA[2][2], lB[2][2];                        // LDS elem offsets (no buf base)
  {
    const int sc = l & 3;
#pragma unroll
    for (int j = 0; j < 2; ++j) {
      const int b = w * 2 + j;
      const int p = b >> 3, s = (b >> 2) & 1, blk = b & 3;
#pragma unroll
      for (int mh = 0; mh < 2; ++mh) {
        const int row = s * 128 + mh * 64 + blk * 16 + (l >> 2);
        const int cl = (sc - (row >> 1)) & 3;
        gA[mh][j] = A + (tileM + row) * (long)K + p * 32 + cl * 8;
        lA[mh][j] = p * 8192 + row * 32 + sc * 8;
      }
      const int rowB = b * 16 + (l >> 2);
      const int clB = (sc - (rowB >> 1)) & 3;
#pragma unroll
      for (int ks = 0; ks < 2; ++ks) {
        gB[ks][j] = B + (tileN + rowB) * (long)K + ks * 32 + clB * 8;
        lB[ks][j] = 16384 + ks * 8192 + rowB * 32 + sc * 8;
      }
    }
  }

  // fragment LDS offsets (logical (r,q) lives at r*32 + ((q+(r>>1))&3)*8)
  int offA[8], offB[4];
#pragma unroll
  for (int mh = 0; mh < 2; ++mh)
#pragma unroll
    for (int mi = 0; mi < 4; ++mi) {
      const int r = wr * 128 + mh * 64 + mi * 16 + m16;
      offA[mh * 4 + mi] = r * 32 + (((q + (r >> 1)) & 3) << 3);
    }
#pragma unroll
  for (int ni = 0; ni < 4; ++ni) {
    const int r = wcn * 64 + ni * 16 + m16;
    offB[ni] = r * 32 + (((q + (r >> 1)) & 3) << 3);
  }

  f32x4 acc[8][4] = {};

#define ST(GP, LO, BUF)                                                        \
  { bf16* bb = ring + (BUF) * 32768;                                           \
    __builtin_amdgcn_global_load_lds(AS1(GP[0]), AS3(bb + LO[0]), 16, 0, 0);   \
    __builtin_amdgcn_global_load_lds(AS1(GP[1]), AS3(bb + LO[1]), 16, 0, 0);   \
    GP[0] += 64; GP[1] += 64; }

  // prologue: tile0 all 4 regions -> buf0; tile1 {A-m0, B-k0} -> buf1.
  // vmcnt(4) = all but last 2 regions -> tile0 fully landed.
  ST(gA[0], lA[0], 0) ST(gB[0], lB[0], 0) ST(gA[1], lA[1], 0) ST(gB[1], lB[1], 0)
  ST(gA[0], lA[0], 1) ST(gB[0], lB[0], 1)
  __builtin_amdgcn_s_waitcnt(VM4);
  __builtin_amdgcn_s_barrier();

  // phase: {8 ds_read_b128, stage, [vmcnt], barrier, lgkm0, prio1, 16 MFMA,
  // prio0, barrier}. Stage targets verified disjoint from all reads that can
  // overlap its in-flight window (see header comment).
#define PHASE(BUF, MH, KS, STG, DOVM, VMW)                                     \
  {                                                                            \
    const bf16* pa = ring + (BUF) * 32768 + (KS) * 8192;                       \
    const bf16* pb = ring + (BUF) * 32768 + 16384 + (KS) * 8192;               \
    bf16x8 af[4], bv[4];                                                       \
    _Pragma("unroll")                                                          \
    for (int mi = 0; mi < 4; ++mi)                                             \
      af[mi] = *(const bf16x8*)&pa[offA[(MH) * 4 + mi]];                       \
    _Pragma("unroll")                                                          \
    for (int ni = 0; ni < 4; ++ni)                                             \
      bv[ni] = *(const bf16x8*)&pb[offB[ni]];                                  \
    STG;                                                                       \
    if (DOVM) __builtin_amdgcn_s_waitcnt(VMW);                                 \
    __builtin_amdgcn_s_barrier();                                              \
    asm volatile("s_waitcnt lgkmcnt(0)");                                      \
    __builtin_amdgcn_s_setprio(1);                                             \
    _Pragma("unroll")                                                          \
    for (int mi = 0; mi < 4; ++mi) {                                           \
      _Pragma("unroll")                                                        \
      for (int ni = 0; ni < 4; ++ni)                                           \
        acc[(MH) * 4 + mi][ni] = __builtin_amdgcn_mfma_f32_16x16x32_bf16(      \
            af[mi], bv[ni], acc[(MH) * 4 + mi][ni], 0, 0, 0);                  \
    }                                                                          \
    __builtin_amdgcn_s_setprio(0);                                             \
    __builtin_amdgcn_s_barrier();                                              \
  }

  // iteration i computes tiles t=2i (buf0, P1-4) and t+1 (buf1, P5-8).
  // stages: P1 buf1.A-m1(t+1), P2 buf1.B-k1(t+1), P3 buf0.A-m0(t+2),
  // P4 buf0.B-k0(t+2)+vm4, P5 buf0.A-m1(t+2), P6 buf0.B-k1(t+2),
  // P7 buf1.A-m0(t+3), P8 buf1.B-k0(t+3)+vm4.
  const int T = K >> 6;   // K-tiles; caller guarantees T even, T >= 4
#pragma unroll 1
  for (int i = 0; i < T / 2 - 1; ++i) {
    PHASE(0, 0, 0, ST(gA[1], lA[1], 1), 0, VM0)
    PHASE(0, 0, 1, ST(gB[1], lB[1], 1), 0, VM0)
    PHASE(0, 1, 0, ST(gA[0], lA[0], 0), 0, VM0)
    PHASE(0, 1, 1, ST(gB[0], lB[0], 0), 1, VM4)
    PHASE(1, 0, 0, ST(gA[1], lA[1], 0), 0, VM0)
    PHASE(1, 0, 1, ST(gB[1], lB[1], 0), 0, VM0)
    PHASE(1, 1, 0, ST(gA[0], lA[0], 1), 0, VM0)
    PHASE(1, 1, 1, ST(gB[0], lB[0], 1), 1, VM4)
  }
  // tail iteration (tiles T-2, T-1): finish staging T-1 at P1/P2, drain.
  PHASE(0, 0, 0, ST(gA[1], lA[1], 1), 0, VM0)
  PHASE(0, 0, 1, ST(gB[1], lB[1], 1), 0, VM0)
  PHASE(0, 1, 0, (void)0, 0, VM0)
  PHASE(0, 1, 1, (void)0, 1, VM0)
  PHASE(1, 0, 0, (void)0, 0, VM0)
  PHASE(1, 0, 1, (void)0, 0, VM0)
  PHASE(1, 1, 0, (void)0, 0, VM0)
  PHASE(1, 1, 1, (void)0, 0, VM0)
#undef PHASE
#undef ST

  // epilogue: C/D layout col = lane&15, row = (lane>>4)*4 + reg (m89-verified)
  const long colBase = tileN + (long)wcn * 64 + m16;
  const long rowBase = tileM + (long)wr * 128 + q * 4;
#pragma unroll
  for (int mi = 0; mi < 8; ++mi) {
#pragma unroll
    for (int r = 0; r < 4; ++r) {
      const long row = rowBase + mi * 16 + r;
#pragma unroll
      for (int ni = 0; ni < 4; ++ni) {
        const long col = colBase + ni * 16;
        float v = acc[mi][ni][r];
        if (EPI == 0) {
          ((bf16*)out)[row * N + col] = (bf16)v;
        } else if (EPI == 1) {
          v += bias[col] + (float)resid[row * N + col];
          ((float*)out)[row * N + col] = v;
        } else if (EPI == 2) {
          v += bias[col];
          v = v > 0.f ? 1.0507009873554805f * v
                      : 1.0507009873554805f * 1.6732632423543772f * (__expf(v) - 1.f);
          ((bf16*)out)[row * N + col] = (bf16)v;
        } else {  // EPI == 3: bf16 = acc + bias + resid
          v += bias[col] + (float)resid[row * N + col];
          ((bf16*)out)[row * N + col] = (bf16)v;
        }
      }
    }
  }
}

// ---------------------------------------------------------------------------
extern "C" void kernel_launch(void* const* d_in, const int* in_sizes, int n_in,
                              void* d_out, int out_size, void* d_ws, size_t ws_size,
                              hipStream_t stream) {
  const float* patches   = (const float*)d_in[0];
  const float* in_weight = (const float*)d_in[1];
  const float* in_bias   = (const float*)d_in[2];
  const float* out_w     = (const float*)d_in[3];
  const float* out_b     = (const float*)d_in[4];
  const float* mlp_w1    = (const float*)d_in[5];
  const float* mlp_b1    = (const float*)d_in[6];
  const float* mlp_w2    = (const float*)d_in[7];
  const float* mlp_b2    = (const float*)d_in[8];
  const float* ln1_g     = (const float*)d_in[9];
  const float* ln1_b     = (const float*)d_in[10];
  const float* ln2_g     = (const float*)d_in[11];
  const float* ln2_b     = (const float*)d_in[12];

  char* ws = (char*)d_ws;
  const size_t MB = 1024 * 1024;
  bf16* Wc   = (bf16*)(ws + 0);        // [768][768] combined proj weight
  bf16* w1b  = (bf16*)(ws + 2 * MB);
  bf16* w2b  = (bf16*)(ws + 8 * MB);
  bf16* owb  = (bf16*)(ws + 14 * MB);
  bf16* wvt  = (bf16*)(ws + 16 * MB);
  float* bc  = (float*)(ws + 18 * MB);
  bf16* X1   = (bf16*)(ws + 20 * MB);  // 25 MB; reused as X3 after proj
  bf16* X3   = (bf16*)(ws + 20 * MB);
  bf16* X2b  = (bf16*)(ws + 48 * MB);  // 25 MB; dead before H written
  bf16* H    = (bf16*)(ws + 48 * MB);  // 100 MB (aliases X2b - safe, see order)

  prep_cast<<<(N1 + N2 + N3) / 256, 256, 0, stream>>>(mlp_w1, mlp_w2, out_w,
                                                      w1b, w2b, owb);
  wvt_kernel<<<dim3(12, 12), 256, 0, stream>>>(in_weight, wvt);
  bias_combine_kernel<<<768, 64, 0, stream>>>(out_w, in_bias, out_b, bc);
  // Wc[n][k] = sum_j out_w[n][j] * WvT[k][j]
  gemm_bt<0><<<dim3(3, 3), 512, 0, stream>>>(owb, wvt, nullptr, nullptr, Wc, 768, 768, 768);

  ln_kernel<float><<<N_ROWS, 256, 0, stream>>>(patches, ln1_g, ln1_b, X1);
  // x2 = x1 @ Wc^T + bc + x1  (bf16)
  gemm_bt<3><<<dim3(3, 64), 512, 0, stream>>>(X1, Wc, bc, X1, X2b, N_ROWS, 768, 768);
  ln_kernel<bf16><<<N_ROWS, 256, 0, stream>>>(X2b, ln2_g, ln2_b, X3);
  // h = selu(x3 @ w1^T + b1)   (overwrites X2b region - X2b is dead)
  gemm_bt<2><<<dim3(12, 64), 512, 0, stream>>>(X3, w1b, mlp_b1, nullptr, H, N_ROWS, 3072, 768);
  // out = h @ w2^T + b2 + x3   (fp32 final)
  gemm_bt<1><<<dim3(3, 64), 512, 0, stream>>>(H, w2b, mlp_b2, X3, d_out, N_ROWS, 768, 3072);
}

// Round 3
// 390.051 us; speedup vs baseline: 1.0244x; 1.0169x over previous
//
#include <hip/hip_runtime.h>

// ============================================================================
// MixerBlock (attention QK^T/softmax is dead code; heads = V only):
//   x1 = LN1(patches); sa = x1 @ Wc^T + bc  (Wc = out_w @ Wv, precomputed)
//   x2 = sa + x1 (bf16, ws); x3 = LN2(x2)
//   h = selu(x3 @ w1^T + b1); out = h @ w2^T + b2 + x3
// R9 = R8 with the first-iteration race fixed (R2 bench was an infra
// failure; FIFO re-trace of R8 found P2's read of b0.A-m1 was never
// vmcnt-forced before iteration 0):
//   - prologue stage order now b0.Am0, b0.Bk0, b0.Am1, b0.Bk1, b1.Bk1,
//     b1.Am1 with WAIT6 (forces first 3 regions = P1+P2's read set).
//   - full FIFO trace verified: P2:WAIT8 covers P3 (b0.Bk1), P4:WAIT6
//     covers P5/P6 (b1.Am0/Bk1/Am1), P6:WAIT8 covers P7 (b1.Bk0),
//     P8:WAIT6 covers next P1/P2; tail WAIT8/WAIT2/WAIT0 cover drain.
// R8 vs R7 (R7 regressed MLP1 109.7->126.8 us: vmcnt slack 2-3 phases,
// B-frags read twice):
//   - read order per 2 K-tiles: (m0,k0)(m1,k0)(m1,k1)(m0,k1) |
//     (m0,k1)(m1,k1)(m1,k0)(m0,k0); B-frags shared across adjacent phase
//     pairs (bv[] live across barriers) -> 24 ds_read_b128/K-tile/wave (-25%).
//   - stage slots at earliest region-free phase; slack >= 4 phases.
//   - exact counted waits (see trace above), never vmcnt(0) in main loop.
// Kept: 256x256/BK=64 tile, 8 waves 2x4 (wave 128x64, acc[8][4]), 128 KiB
// 2-K-tile LDS, 16x16x32 MFMA, chunk swizzle, global_load_lds w16, setprio,
// XCD m-band remap, bf16 X2 residency, merged casts.
// ============================================================================

typedef __bf16 bf16;
typedef __bf16 bf16x8 __attribute__((ext_vector_type(8)));
typedef __bf16 bf16x4 __attribute__((ext_vector_type(4)));
typedef float  f32x4  __attribute__((ext_vector_type(4)));

#define N_ROWS  16384   // B*S = 8*2048

#define AS1(p) ((const __attribute__((address_space(1))) void*)(p))
#define AS3(p) ((__attribute__((address_space(3))) void*)(p))

// s_waitcnt imm (gfx9): vmcnt[3:0]|[15:14], expcnt[6:4]=7, lgkmcnt[11:8]=0xF
#define WAIT8  __builtin_amdgcn_s_waitcnt(0x0F78)
#define WAIT6  __builtin_amdgcn_s_waitcnt(0x0F76)
#define WAIT2  __builtin_amdgcn_s_waitcnt(0x0F72)
#define WAIT0  __builtin_amdgcn_s_waitcnt(0x0F70)
#define NOWAIT (void)0

// ---------------------------------------------------------------------------
// merged fp32->bf16 casts: mlp_w1 | mlp_w2 | out_w (4 elems/thread)
#define N1 589824   // 3072*768/4
#define N2 589824   // 768*3072/4
#define N3 147456   // 768*768/4
__global__ __launch_bounds__(256) void prep_cast(const float* __restrict__ w1,
                                                 const float* __restrict__ w2,
                                                 const float* __restrict__ ow,
                                                 bf16* __restrict__ w1b,
                                                 bf16* __restrict__ w2b,
                                                 bf16* __restrict__ owb) {
  int i = blockIdx.x * 256 + threadIdx.x;
  const float* src; bf16* dst; int off;
  if (i < N1)           { src = w1; dst = w1b; off = i; }
  else if (i < N1 + N2) { src = w2; dst = w2b; off = i - N1; }
  else                  { src = ow; dst = owb; off = i - N1 - N2; }
  float4 v = ((const float4*)src)[off];
  bf16x4 o = {(bf16)v.x, (bf16)v.y, (bf16)v.z, (bf16)v.w};
  *(bf16x4*)(dst + 4 * (size_t)off) = o;
}

// ---------------------------------------------------------------------------
// WvT[k][j] = in_weight[(j*3+2)*768 + k], LDS-tiled 64x64 (coalesced both ways)
__global__ __launch_bounds__(256) void wvt_kernel(const float* __restrict__ in_weight,
                                                  bf16* __restrict__ wvt) {
  __shared__ float t[64][65];
  const int k0 = blockIdx.x * 64, j0 = blockIdx.y * 64;
  const int tx = threadIdx.x & 63, ty = threadIdx.x >> 6;
  for (int jj = ty; jj < 64; jj += 4)
    t[jj][tx] = in_weight[((size_t)(j0 + jj) * 3 + 2) * 768 + k0 + tx];
  __syncthreads();
  for (int kk = ty; kk < 64; kk += 4)
    wvt[(size_t)(k0 + kk) * 768 + j0 + tx] = (bf16)t[tx][kk];
}

// ---------------------------------------------------------------------------
__global__ __launch_bounds__(64) void bias_combine_kernel(const float* __restrict__ out_w,
                                                          const float* __restrict__ in_bias,
                                                          const float* __restrict__ out_b,
                                                          float* __restrict__ bc) {
  int n = blockIdx.x, l = threadIdx.x;
  float s = 0.f;
  for (int j = l; j < 768; j += 64) s += out_w[(size_t)n * 768 + j] * in_bias[j * 3 + 2];
#pragma unroll
  for (int off = 32; off > 0; off >>= 1) s += __shfl_xor(s, off, 64);
  if (l == 0) bc[n] = s + out_b[n];
}

// ---------------------------------------------------------------------------
// LayerNorm: one row (768) per 256-thread block. TIN = float or bf16.
template <typename TIN>
__global__ __launch_bounds__(256) void ln_kernel(const TIN* __restrict__ x,
                                                 const float* __restrict__ g,
                                                 const float* __restrict__ b,
                                                 bf16* __restrict__ y) {
  const int row = blockIdx.x;
  const TIN* xr = x + (size_t)row * 768;
  float v[3], s1 = 0.f, s2 = 0.f;
#pragma unroll
  for (int i = 0; i < 3; ++i) {
    v[i] = (float)xr[threadIdx.x + i * 256];
    s1 += v[i];
    s2 += v[i] * v[i];
  }
#pragma unroll
  for (int off = 32; off > 0; off >>= 1) {
    s1 += __shfl_xor(s1, off, 64);
    s2 += __shfl_xor(s2, off, 64);
  }
  __shared__ float red[8];
  int w = threadIdx.x >> 6, l = threadIdx.x & 63;
  if (l == 0) { red[w * 2] = s1; red[w * 2 + 1] = s2; }
  __syncthreads();
  s1 = red[0] + red[2] + red[4] + red[6];
  s2 = red[1] + red[3] + red[5] + red[7];
  const float mu = s1 * (1.f / 768.f);
  const float var = s2 * (1.f / 768.f) - mu * mu;
  const float rstd = rsqrtf(var + 1e-5f);
#pragma unroll
  for (int i = 0; i < 3; ++i) {
    int d = threadIdx.x + i * 256;
    y[(size_t)row * 768 + d] = (bf16)((v[i] - mu) * rstd * g[d] + b[d]);
  }
}

// ---------------------------------------------------------------------------
// C[M][N] = A[M][K] @ B[N][K]^T (+ epilogue). Block tile 256x256, BK=64,
// 512 threads = 8 waves (2x4), wave tile 128x64, acc[8][4].
// 8-phase schedule over 2 K-tiles (double-buffered 128 KiB LDS).
// LDS per buffer: A [2 k-panels][256 rows][32 k] + B same, chunk-swizzled
// (stored 16B chunk sc at row r holds logical chunk (sc-(r>>1))&3).
// Regions (16 KB, 2 loads/thread): A-m0 = block rows {0-63,128-191} (each
// wave's rows 0-63), A-m1 = rows {64-127,192-255}, B-k0/B-k1 = k-panels.
// Read order: P1(b0,m0,k0) P2(b0,m1,k0) P3(b0,m1,k1) P4(b0,m0,k1)
//             P5(b1,m0,k1) P6(b1,m1,k1) P7(b1,m1,k0) P8(b1,m0,k0)
//   -> B-frags shared across pairs (P1,P2)(P3,P4)(P5,P6)(P7,P8).
// Stage slots (region free -> first read, slack >=4 phases):
//   P1: b1.A-m0(t+1)  P2: b1.B-k0(t+1)  P3: b0.B-k0(t+2)  P4: b0.A-m1(t+2)
//   P5: b0.A-m0(t+2)  P6: b0.B-k1(t+2)  P7: b1.B-k1(t+3)  P8: b1.A-m1(t+3)
// Waits (wait at phase P + barrier protects reads of phases > P):
//   prologue WAIT6 covers P1+P2; P2:WAIT8 -> P3; P4:WAIT6 -> P5,P6;
//   P6:WAIT8 -> P7; P8:WAIT6 -> next P1,P2. (FIFO-trace verified.)
// Requires K % 128 == 0, K >= 256; M,N % 256 == 0.
// EPI 0: bf16=acc | EPI 1: f32=acc+bias+resid | EPI 2: bf16=selu(acc+bias)
// EPI 3: bf16=acc+bias+resid
template <int EPI>
__global__ __launch_bounds__(512, 2) void gemm_bt(const bf16* __restrict__ A,
                                                  const bf16* __restrict__ B,
                                                  const float* __restrict__ bias,
                                                  const bf16* __restrict__ resid,
                                                  void* __restrict__ out,
                                                  int M, int N, int K) {
  __shared__ bf16 ring[65536];   // 128 KiB = 2 bufs x (A 16384 + B 16384 elems)
  const int tid = threadIdx.x;
  const int w = tid >> 6, l = tid & 63;
  const int wr = w >> 2, wcn = w & 3;       // 2x4 wave grid
  const int q = l >> 4, m16 = l & 15;

  // XCD-aware remap (XCD = linear%8): each XCD owns a contiguous band of
  // gridy/8 m-strips, m fastest -> A band L2-resident across n-tiles.
  int mtile, ntile;
  {
    const int L = blockIdx.y * gridDim.x + blockIdx.x;
    const int gy = gridDim.y;
    if ((gy & 7) == 0) {
      const int mpx = gy >> 3;
      const int xcd = L & 7;
      const int slot = L >> 3;
      mtile = xcd * mpx + (slot % mpx);
      ntile = slot / mpx;
    } else {
      mtile = blockIdx.y; ntile = blockIdx.x;
    }
  }
  const long tileM = (long)mtile * 256;
  const long tileN = (long)ntile * 256;

  // staging geometry: per region 16 blocks of 1 KB (16 rows x 64 B), block
  // b = w*2+j; lane l covers row (l>>2), stored chunk (l&3) -> LDS dest is
  // wave-uniform base + l*16B (global_load_lds constraint). Global source is
  // pre-swizzled per-lane. Region k-advance handled via uniform koff vars.
  const bf16* gA[2][2]; const bf16* gB[2][2];   // [mh|ks][j] base at k=0
  int lA[2][2], lB[2][2];                        // LDS elem offsets (no buf base)
  {
    const int sc = l & 3;
#pragma unroll
    for (int j = 0; j < 2; ++j) {
      const int b = w * 2 + j;
      const int p = b >> 3, s = (b >> 2) & 1, blk = b & 3;
#pragma unroll
      for (int mh = 0; mh < 2; ++mh) {
        const int row = s * 128 + mh * 64 + blk * 16 + (l >> 2);
        const int cl = (sc - (row >> 1)) & 3;
        gA[mh][j] = A + (tileM + row) * (long)K + p * 32 + cl * 8;
        lA[mh][j] = p * 8192 + row * 32 + sc * 8;
      }
      const int rowB = b * 16 + (l >> 2);
      const int clB = (sc - (rowB >> 1)) & 3;
#pragma unroll
      for (int ks = 0; ks < 2; ++ks) {
        gB[ks][j] = B + (tileN + rowB) * (long)K + ks * 32 + clB * 8;
        lB[ks][j] = 16384 + ks * 8192 + rowB * 32 + sc * 8;
      }
    }
  }

  // fragment LDS offsets (logical (r,q) lives at r*32 + ((q+(r>>1))&3)*8)
  int offA[8], offB[4];
#pragma unroll
  for (int mh = 0; mh < 2; ++mh)
#pragma unroll
    for (int mi = 0; mi < 4; ++mi) {
      const int r = wr * 128 + mh * 64 + mi * 16 + m16;
      offA[mh * 4 + mi] = r * 32 + (((q + (r >> 1)) & 3) << 3);
    }
#pragma unroll
  for (int ni = 0; ni < 4; ++ni) {
    const int r = wcn * 64 + ni * 16 + m16;
    offB[ni] = r * 32 + (((q + (r >> 1)) & 3) << 3);
  }

  f32x4 acc[8][4] = {};

  // per-region k offsets (wave-uniform, elements). +128 (2 tiles) per stage.
  int kb0A0 = 0, kb0B0 = 0, kb0B1 = 0, kb0A1 = 0;
  int kb1A0 = 64, kb1B0 = 64, kb1B1 = 64, kb1A1 = 64;

#define ST(BP, LO, BUF, KV)                                                    \
  { bf16* bb = ring + (BUF) * 32768;                                           \
    __builtin_amdgcn_global_load_lds(AS1((BP)[0] + (KV)), AS3(bb + (LO)[0]), 16, 0, 0); \
    __builtin_amdgcn_global_load_lds(AS1((BP)[1] + (KV)), AS3(bb + (LO)[1]), 16, 0, 0); \
    (KV) += 128; }

  // prologue: b0 all 4 regions (tile 0) ordered {Am0, Bk0, Am1, Bk1}, then
  // b1.{Bk1, Am1} (tile 1). WAIT6 -> first 3 regions (P1's and P2's read
  // set: b0.Am0, b0.Bk0, b0.Am1) landed before the first barrier.
  ST(gA[0], lA[0], 0, kb0A0) ST(gB[0], lB[0], 0, kb0B0)
  ST(gA[1], lA[1], 0, kb0A1) ST(gB[1], lB[1], 0, kb0B1)
  ST(gB[1], lB[1], 1, kb1B1) ST(gA[1], lA[1], 1, kb1A1)
  WAIT6;
  __builtin_amdgcn_s_barrier();

  // phase: {4 A-ds_reads (+4 B if LB), stage, [wait], barrier, lgkm0,
  // prio1, 16 MFMA, prio0, barrier}. bv persists across each phase pair.
  bf16x8 bv[4];
#define PHASE(BUF, MH, KS, LB, STG, WSTMT)                                     \
  {                                                                            \
    const bf16* pa = ring + (BUF) * 32768 + (KS) * 8192;                       \
    const bf16* pb = ring + (BUF) * 32768 + 16384 + (KS) * 8192;               \
    bf16x8 af[4];                                                              \
    _Pragma("unroll")                                                          \
    for (int mi = 0; mi < 4; ++mi)                                             \
      af[mi] = *(const bf16x8*)&pa[offA[(MH) * 4 + mi]];                       \
    if (LB) {                                                                  \
      _Pragma("unroll")                                                        \
      for (int ni = 0; ni < 4; ++ni)                                           \
        bv[ni] = *(const bf16x8*)&pb[offB[ni]];                                \
    }                                                                          \
    STG;                                                                       \
    WSTMT;                                                                     \
    __builtin_amdgcn_s_barrier();                                              \
    asm volatile("s_waitcnt lgkmcnt(0)");                                      \
    __builtin_amdgcn_s_setprio(1);                                             \
    _Pragma("unroll")                                                          \
    for (int mi = 0; mi < 4; ++mi) {                                           \
      _Pragma("unroll")                                                        \
      for (int ni = 0; ni < 4; ++ni)                                           \
        acc[(MH) * 4 + mi][ni] = __builtin_amdgcn_mfma_f32_16x16x32_bf16(      \
            af[mi], bv[ni], acc[(MH) * 4 + mi][ni], 0, 0, 0);                  \
    }                                                                          \
    __builtin_amdgcn_s_setprio(0);                                             \
    __builtin_amdgcn_s_barrier();                                              \
  }

  const int T = K >> 6;   // K-tiles; caller guarantees T even, T >= 4
#pragma unroll 1
  for (int i = 0; i < T / 2 - 1; ++i) {
    PHASE(0, 0, 0, 1, ST(gA[0], lA[0], 1, kb1A0), NOWAIT)   // P1
    PHASE(0, 1, 0, 0, ST(gB[0], lB[0], 1, kb1B0), WAIT8)    // P2
    PHASE(0, 1, 1, 1, ST(gB[0], lB[0], 0, kb0B0), NOWAIT)   // P3
    PHASE(0, 0, 1, 0, ST(gA[1], lA[1], 0, kb0A1), WAIT6)    // P4
    PHASE(1, 0, 1, 1, ST(gA[0], lA[0], 0, kb0A0), NOWAIT)   // P5
    PHASE(1, 1, 1, 0, ST(gB[1], lB[1], 0, kb0B1), WAIT8)    // P6
    PHASE(1, 1, 0, 1, ST(gB[1], lB[1], 1, kb1B1), NOWAIT)   // P7
    PHASE(1, 0, 0, 0, ST(gA[1], lA[1], 1, kb1A1), WAIT6)    // P8
  }
  // tail (tiles T-2, T-1): finish b1 staging at P1/P2, exact drain waits.
  PHASE(0, 0, 0, 1, ST(gA[0], lA[0], 1, kb1A0), NOWAIT)
  PHASE(0, 1, 0, 0, ST(gB[0], lB[0], 1, kb1B0), WAIT8)
  PHASE(0, 1, 1, 1, (void)0, NOWAIT)
  PHASE(0, 0, 1, 0, (void)0, WAIT2)
  PHASE(1, 0, 1, 1, (void)0, NOWAIT)
  PHASE(1, 1, 1, 0, (void)0, WAIT0)
  PHASE(1, 1, 0, 1, (void)0, NOWAIT)
  PHASE(1, 0, 0, 0, (void)0, NOWAIT)
#undef PHASE
#undef ST

  // epilogue: C/D layout col = lane&15, row = (lane>>4)*4 + reg (m89-verified)
  const long colBase = tileN + (long)wcn * 64 + m16;
  const long rowBase = tileM + (long)wr * 128 + q * 4;
#pragma unroll
  for (int mi = 0; mi < 8; ++mi) {
#pragma unroll
    for (int r = 0; r < 4; ++r) {
      const long row = rowBase + mi * 16 + r;
#pragma unroll
      for (int ni = 0; ni < 4; ++ni) {
        const long col = colBase + ni * 16;
        float v = acc[mi][ni][r];
        if (EPI == 0) {
          ((bf16*)out)[row * N + col] = (bf16)v;
        } else if (EPI == 1) {
          v += bias[col] + (float)resid[row * N + col];
          ((float*)out)[row * N + col] = v;
        } else if (EPI == 2) {
          v += bias[col];
          v = v > 0.f ? 1.0507009873554805f * v
                      : 1.0507009873554805f * 1.6732632423543772f * (__expf(v) - 1.f);
          ((bf16*)out)[row * N + col] = (bf16)v;
        } else {  // EPI == 3: bf16 = acc + bias + resid
          v += bias[col] + (float)resid[row * N + col];
          ((bf16*)out)[row * N + col] = (bf16)v;
        }
      }
    }
  }
}

// ---------------------------------------------------------------------------
extern "C" void kernel_launch(void* const* d_in, const int* in_sizes, int n_in,
                              void* d_out, int out_size, void* d_ws, size_t ws_size,
                              hipStream_t stream) {
  const float* patches   = (const float*)d_in[0];
  const float* in_weight = (const float*)d_in[1];
  const float* in_bias   = (const float*)d_in[2];
  const float* out_w     = (const float*)d_in[3];
  const float* out_b     = (const float*)d_in[4];
  const float* mlp_w1    = (const float*)d_in[5];
  const float* mlp_b1    = (const float*)d_in[6];
  const float* mlp_w2    = (const float*)d_in[7];
  const float* mlp_b2    = (const float*)d_in[8];
  const float* ln1_g     = (const float*)d_in[9];
  const float* ln1_b     = (const float*)d_in[10];
  const float* ln2_g     = (const float*)d_in[11];
  const float* ln2_b     = (const float*)d_in[12];

  char* ws = (char*)d_ws;
  const size_t MB = 1024 * 1024;
  bf16* Wc   = (bf16*)(ws + 0);        // [768][768] combined proj weight
  bf16* w1b  = (bf16*)(ws + 2 * MB);
  bf16* w2b  = (bf16*)(ws + 8 * MB);
  bf16* owb  = (bf16*)(ws + 14 * MB);
  bf16* wvt  = (bf16*)(ws + 16 * MB);
  float* bc  = (float*)(ws + 18 * MB);
  bf16* X1   = (bf16*)(ws + 20 * MB);  // 25 MB; reused as X3 after proj
  bf16* X3   = (bf16*)(ws + 20 * MB);
  bf16* X2b  = (bf16*)(ws + 48 * MB);  // 25 MB; dead before H written
  bf16* H    = (bf16*)(ws + 48 * MB);  // 100 MB (aliases X2b - safe, see order)

  prep_cast<<<(N1 + N2 + N3) / 256, 256, 0, stream>>>(mlp_w1, mlp_w2, out_w,
                                                      w1b, w2b, owb);
  wvt_kernel<<<dim3(12, 12), 256, 0, stream>>>(in_weight, wvt);
  bias_combine_kernel<<<768, 64, 0, stream>>>(out_w, in_bias, out_b, bc);
  // Wc[n][k] = sum_j out_w[n][j] * WvT[k][j]
  gemm_bt<0><<<dim3(3, 3), 512, 0, stream>>>(owb, wvt, nullptr, nullptr, Wc, 768, 768, 768);

  ln_kernel<float><<<N_ROWS, 256, 0, stream>>>(patches, ln1_g, ln1_b, X1);
  // x2 = x1 @ Wc^T + bc + x1  (bf16)
  gemm_bt<3><<<dim3(3, 64), 512, 0, stream>>>(X1, Wc, bc, X1, X2b, N_ROWS, 768, 768);
  ln_kernel<bf16><<<N_ROWS, 256, 0, stream>>>(X2b, ln2_g, ln2_b, X3);
  // h = selu(x3 @ w1^T + b1)   (overwrites X2b region - X2b is dead)
  gemm_bt<2><<<dim3(12, 64), 512, 0, stream>>>(X3, w1b, mlp_b1, nullptr, H, N_ROWS, 3072, 768);
  // out = h @ w2^T + b2 + x3   (fp32 final)
  gemm_bt<1><<<dim3(3, 64), 512, 0, stream>>>(H, w2b, mlp_b2, X3, d_out, N_ROWS, 768, 3072);
}